// Round 4
// baseline (281.558 us; speedup 1.0000x reference)
//
#include <hip/hip_runtime.h>

typedef __bf16 bf16x8 __attribute__((ext_vector_type(8)));
typedef float f32x4 __attribute__((ext_vector_type(4)));

#define DEV __device__ __forceinline__

DEV unsigned short f2bf(float f) {
  union { float f; unsigned u; } x; x.f = f;
  unsigned r = x.u + 0x7FFFu + ((x.u >> 16) & 1u);  // RNE
  return (unsigned short)(r >> 16);
}
DEV float bf2f(unsigned short h) {
  union { unsigned u; float f; } x; x.u = ((unsigned)h) << 16;
  return x.f;
}

typedef __attribute__((address_space(3))) void* lds_vp;
typedef const __attribute__((address_space(1))) void* gbl_vp;
DEV void load_lds16(const unsigned short* gp, void* lp) {
  __builtin_amdgcn_global_load_lds((gbl_vp)(const void*)gp, (lds_vp)lp, 16, 0, 0);
}

// ---- dtype detector: f32 buffers read as bf16 show mantissa-noise exponents
__global__ void detect_dtype_k(const unsigned short* __restrict__ x,
                               int* __restrict__ flag) {
  __shared__ int cnt;
  if (threadIdx.x == 0) cnt = 0;
  __syncthreads();
  int c = 0;
  for (int i = threadIdx.x; i < 8192; i += 256) {
    unsigned e = (x[i] >> 7) & 0xFFu;
    c += (e >= 0xC0u) ? 1 : 0;
  }
  atomicAdd(&cnt, c);
  __syncthreads();
  if (threadIdx.x == 0) *flag = (cnt > 64) ? 1 : 0;
}

// ---- fused convert: x (2097152) | rel (65600) | bo (1024) -> bf16
__global__ void cvt_all_k(const void* __restrict__ xs, const void* __restrict__ rs,
                          const void* __restrict__ bs,
                          unsigned short* __restrict__ xd,
                          unsigned short* __restrict__ rd,
                          unsigned short* __restrict__ bd,
                          const int* __restrict__ flag) {
  const int f = *flag;
  const int NX = 2097152, NR = 65600, NB = 1024;
  for (int i = blockIdx.x * 256 + threadIdx.x; i < NX + NR + NB; i += gridDim.x * 256) {
    const void* src; unsigned short* dst; int j;
    if (i < NX)            { src = xs; dst = xd; j = i; }
    else if (i < NX + NR)  { src = rs; dst = rd; j = i - NX; }
    else                   { src = bs; dst = bd; j = i - NX - NR; }
    dst[j] = f ? f2bf(((const float*)src)[j]) : ((const unsigned short*)src)[j];
  }
}

// ---- fused transpose+convert of the three weights: dst[C][R] = src[R][C]
__global__ void transpose_all_k(const void* __restrict__ Wq, const void* __restrict__ Wkv,
                                const void* __restrict__ Wo,
                                unsigned short* __restrict__ dq,   // also Wkv dst at +1048576
                                unsigned short* __restrict__ dо_unused,
                                unsigned short* __restrict__ dwo,
                                const int* __restrict__ flag) {
  __shared__ unsigned short tile[32][33];
  const int f = *flag;
  int id = blockIdx.x;
  const void* src; unsigned short* dst; int R = 1024, C; int tx_t, ty_t;
  if (id < 1024)       { src = Wq;  dst = dq;            C = 1024; tx_t = id & 31;  ty_t = id >> 5; }
  else if (id < 3072)  { int l = id - 1024; src = Wkv; dst = dq + 1048576; C = 2048; tx_t = l & 63; ty_t = l >> 6; }
  else                 { int l = id - 3072; src = Wo;  dst = dwo;          C = 1024; tx_t = l & 31; ty_t = l >> 5; }
  const float* sf = (const float*)src;
  const unsigned short* su = (const unsigned short*)src;
  int c0 = tx_t * 32, r0 = ty_t * 32;
  int tx = threadIdx.x & 31, ty = threadIdx.x >> 5;  // 32x8
  #pragma unroll
  for (int i = 0; i < 4; ++i) {
    size_t idx = (size_t)(r0 + ty + i * 8) * C + c0 + tx;
    tile[ty + i * 8][tx] = f ? f2bf(sf[idx]) : su[idx];
  }
  __syncthreads();
  #pragma unroll
  for (int i = 0; i < 4; ++i)
    dst[(size_t)(c0 + ty + i * 8) * R + r0 + tx] = tile[tx][ty + i * 8];
}

// ---- per-head V transpose: v[bh][n][d] -> vT[bh][d][n]
__global__ __launch_bounds__(256)
void transpose_v_k(const unsigned short* __restrict__ v,
                   unsigned short* __restrict__ vt) {
  __shared__ __align__(16) unsigned short st[64][68];
  const int bh = blockIdx.y, n0 = blockIdx.x * 64;
  const unsigned short* vp = v + (size_t)bh * 1024 * 64;
  unsigned short* tp = vt + (size_t)bh * 64 * 1024;
  #pragma unroll
  for (int cc = 0; cc < 2; ++cc) {
    int ci = threadIdx.x + cc * 256;
    int row = ci >> 3, dc = (ci & 7) * 8;
    *(uint4*)&st[row][dc] = *(const uint4*)&vp[(size_t)(n0 + row) * 64 + dc];
  }
  __syncthreads();
  #pragma unroll
  for (int cc = 0; cc < 2; ++cc) {
    int ci = threadIdx.x + cc * 256;
    int d = ci >> 3, nc = (ci & 7) * 8;
    union { uint4 v; unsigned short us[8]; } t;
    #pragma unroll
    for (int e = 0; e < 8; ++e) t.us[e] = st[nc + e][d];
    *(uint4*)&tp[(size_t)d * 1024 + n0 + nc] = t.v;
  }
}

// ---------------- GEMM C = A @ Bt^T  (A[M][K], Bt[N][K], bf16) -------------
// 128x128 tile, BK=32, global_load_lds width-16 staging (m97 structure).
// mode 1: split cols into q/k/v (bf16, [b,h,n,d]). mode 2: +bias, f32 out.
__global__ __launch_bounds__(256)
void gemm_bt(const unsigned short* __restrict__ A,
             const unsigned short* __restrict__ Bt,
             int M, int N, int K, int mode,
             const unsigned short* __restrict__ bias,
             unsigned short* __restrict__ o0,
             unsigned short* __restrict__ o1,
             unsigned short* __restrict__ o2,
             float* __restrict__ fo) {
  __shared__ __align__(16) unsigned short As[128][32];  // unpadded: load_lds dest
  __shared__ __align__(16) unsigned short Bs[128][32];
  const int tid  = threadIdx.x;
  const int lane = tid & 63, wave = tid >> 6;
  const int q15  = lane & 15, quad = lane >> 4;
  const int wr = wave >> 1, wc = wave & 1;
  const int m0 = blockIdx.y * 128, n0 = blockIdx.x * 128;

  const int lrow = lane >> 2, lkc = (lane & 3) * 8;

  f32x4 acc[4][4] = {};

  for (int k0 = 0; k0 < K; k0 += 32) {
    __syncthreads();
    #pragma unroll
    for (int t = 0; t < 2; ++t) {
      int r0 = wave * 32 + t * 16;
      load_lds16(&A[(size_t)(m0 + r0 + lrow) * K + k0 + lkc], &As[r0][0]);
      load_lds16(&Bt[(size_t)(n0 + r0 + lrow) * K + k0 + lkc], &Bs[r0][0]);
    }
    __syncthreads();
    bf16x8 af[4], bfr[4];
    #pragma unroll
    for (int i = 0; i < 4; ++i) {
      af[i]  = *(const bf16x8*)&As[wr * 64 + i * 16 + q15][quad * 8];
      bfr[i] = *(const bf16x8*)&Bs[wc * 64 + i * 16 + q15][quad * 8];
    }
    #pragma unroll
    for (int i = 0; i < 4; ++i)
      #pragma unroll
      for (int j = 0; j < 4; ++j)
        acc[i][j] = __builtin_amdgcn_mfma_f32_16x16x32_bf16(af[i], bfr[j], acc[i][j], 0, 0, 0);
  }

  // epilogue — C/D layout: col = lane&15, row = quad*4 + r
  #pragma unroll
  for (int i = 0; i < 4; ++i)
    #pragma unroll
    for (int j = 0; j < 4; ++j)
      #pragma unroll
      for (int r = 0; r < 4; ++r) {
        int row = m0 + wr * 64 + i * 16 + quad * 4 + r;
        int col = n0 + wc * 64 + j * 16 + q15;
        float v = acc[i][j][r];
        if (mode == 2) {
          fo[(size_t)row * N + col] = v + bf2f(bias[col]);
        } else {
          int b = row >> 10, nn = row & 1023;
          unsigned short* dst; int c = col;
          if (col < 1024)      { dst = o0; }
          else if (col < 2048) { dst = o1; c = col - 1024; }
          else                 { dst = o2; c = col - 2048; }
          int h = c >> 6, dd = c & 63;
          dst[((size_t)(b * 16 + h) * 1024 + nn) * 64 + dd] = f2bf(v);
        }
      }
}

// ---------------- flash attention, barrier-free -----------------------------
// grid (16 i-tiles, 32 bh); 4 waves x 16 Q-rows; j-tiles of 64.
// All LDS is per-wave -> zero __syncthreads. K, V^T, rel read from L2.
__global__ __launch_bounds__(256)
void flash_attn(const unsigned short* __restrict__ q_ws,
                const unsigned short* __restrict__ k_ws,
                const unsigned short* __restrict__ vt_ws,  // [bh][64][1024]
                const unsigned short* __restrict__ rel,    // [1025][64]
                unsigned short* __restrict__ ao) {         // [2048][1024]
  __shared__ __align__(16) float T_lds[4][16][84];           // stride 84: 2-way=free
  __shared__ __align__(16) unsigned short P_lds[4][16][72];

  const int tid  = threadIdx.x;
  const int lane = tid & 63, w = tid >> 6;
  const int q15  = lane & 15, quad = lane >> 4;
  const int bh = blockIdx.y;
  const int ib = blockIdx.x * 64 + w * 16;

  const unsigned short* qp = q_ws  + (size_t)bh * 1024 * 64;
  const unsigned short* kp = k_ws  + (size_t)bh * 1024 * 64;
  const unsigned short* tp = vt_ws + (size_t)bh * 64 * 1024;

  // Q strip, A-layout, pre-scaled by 0.125 (exact exponent shift)
  bf16x8 aq[2];
  #pragma unroll
  for (int ks = 0; ks < 2; ++ks) {
    const unsigned short* qrow = &qp[(size_t)(ib + q15) * 64 + ks * 32 + quad * 8];
    #pragma unroll
    for (int e = 0; e < 8; ++e)
      ((unsigned short*)&aq[ks])[e] = f2bf(bf2f(qrow[e]) * 0.125f);
  }

  f32x4 o[4] = {};
  float m_i[4], l_i[4];
  #pragma unroll
  for (int r = 0; r < 4; ++r) { m_i[r] = -60000.f; l_i[r] = 0.f; }

  #pragma unroll 2
  for (int j0 = 0; j0 < 1024; j0 += 64) {
    // Q K^T
    f32x4 accS[4] = {};
    #pragma unroll
    for (int ks = 0; ks < 2; ++ks)
      #pragma unroll
      for (int cb = 0; cb < 4; ++cb) {
        bf16x8 bk = *(const bf16x8*)&kp[(size_t)(j0 + cb * 16 + q15) * 64 + ks * 32 + quad * 8];
        accS[cb] = __builtin_amdgcn_mfma_f32_16x16x32_bf16(aq[ks], bk, accS[cb], 0, 0, 0);
      }
    // positional band T[16][80]
    int tb = ib - j0 + 512 - 63;
    f32x4 accT[5] = {};
    #pragma unroll
    for (int ks = 0; ks < 2; ++ks)
      #pragma unroll
      for (int ub = 0; ub < 5; ++ub) {
        int trow = tb + ub * 16 + q15;
        trow = trow < 0 ? 0 : (trow > 1024 ? 1024 : trow);
        bf16x8 br = *(const bf16x8*)&rel[(size_t)trow * 64 + ks * 32 + quad * 8];
        accT[ub] = __builtin_amdgcn_mfma_f32_16x16x32_bf16(aq[ks], br, accT[ub], 0, 0, 0);
      }
    #pragma unroll
    for (int ub = 0; ub < 5; ++ub)
      #pragma unroll
      for (int r = 0; r < 4; ++r)
        T_lds[w][quad * 4 + r][ub * 16 + q15] = accT[ub][r];
    // per-wave LDS: no barrier, compiler inserts lgkmcnt waits

    float s[4][4];
    #pragma unroll
    for (int cb = 0; cb < 4; ++cb)
      #pragma unroll
      for (int r = 0; r < 4; ++r) {
        int dl = quad * 4 + r, dj = cb * 16 + q15;
        s[cb][r] = accS[cb][r] + T_lds[w][dl][63 + dl - dj];
      }
    #pragma unroll
    for (int r = 0; r < 4; ++r) {
      float mx = fmaxf(fmaxf(s[0][r], s[1][r]), fmaxf(s[2][r], s[3][r]));
      #pragma unroll
      for (int off = 1; off < 16; off <<= 1)
        mx = fmaxf(mx, __shfl_xor(mx, off, 64));
      float mnew = fmaxf(m_i[r], mx);
      float alpha = exp2f(fmaxf((m_i[r] - mnew) * 1.44269504f, -126.f));
      m_i[r] = mnew;
      float pr[4], sum = 0.f;
      #pragma unroll
      for (int cb = 0; cb < 4; ++cb) {
        pr[cb] = exp2f(fmaxf((s[cb][r] - mnew) * 1.44269504f, -126.f));
        sum += pr[cb];
      }
      #pragma unroll
      for (int off = 1; off < 16; off <<= 1)
        sum += __shfl_xor(sum, off, 64);
      l_i[r] = l_i[r] * alpha + sum;
      #pragma unroll
      for (int db = 0; db < 4; ++db) o[db][r] *= alpha;
      #pragma unroll
      for (int cb = 0; cb < 4; ++cb)
        P_lds[w][quad * 4 + r][cb * 16 + q15] = f2bf(pr[cb]);
    }

    // O += P @ V   (P via per-wave LDS round-trip; V^T B-frags from global)
    #pragma unroll
    for (int ks = 0; ks < 2; ++ks) {
      bf16x8 ap = *(const bf16x8*)&P_lds[w][q15][ks * 32 + quad * 8];
      #pragma unroll
      for (int db = 0; db < 4; ++db) {
        bf16x8 bv = *(const bf16x8*)&tp[(size_t)(db * 16 + q15) * 1024 + j0 + ks * 32 + quad * 8];
        o[db] = __builtin_amdgcn_mfma_f32_16x16x32_bf16(ap, bv, o[db], 0, 0, 0);
      }
    }
  }

  int b = bh >> 4, h = bh & 15;
  #pragma unroll
  for (int db = 0; db < 4; ++db)
    #pragma unroll
    for (int r = 0; r < 4; ++r) {
      int row = ib + quad * 4 + r;
      float val = o[db][r] / l_i[r];
      ao[((size_t)(b * 1024 + row)) * 1024 + h * 64 + db * 16 + q15] = f2bf(val);
    }
}

// ---------------------------------------------------------------------------
extern "C" void kernel_launch(void* const* d_in, const int* in_sizes, int n_in,
                              void* d_out, int out_size, void* d_ws, size_t ws_size,
                              hipStream_t stream) {
  (void)in_sizes; (void)n_in; (void)out_size; (void)ws_size;
  const void* x   = d_in[0];
  const void* Wq  = d_in[1];
  const void* Wkv = d_in[2];
  const void* Wo  = d_in[3];
  const void* bo  = d_in[4];
  const void* rel = d_in[5];
  float* out = (float*)d_out;

  unsigned short* ws = (unsigned short*)d_ws;
  unsigned short* xb    = ws;                     // 2,097,152
  unsigned short* WqkvT = xb    + 2097152;        // 3,145,728 (vT aliases later)
  unsigned short* WoT   = WqkvT + 3145728;        // 1,048,576
  unsigned short* relb  = WoT   + 1048576;        // 65,664 reserved
  unsigned short* bob   = relb  + 65664;          // 1024
  int*            flagp = (int*)(bob + 1024);     // 64 reserved
  unsigned short* q_ws  = bob   + 1024 + 64;
  unsigned short* k_ws  = q_ws  + 2097152;
  unsigned short* v_ws  = k_ws  + 2097152;
  unsigned short* ao    = xb;      // alias: xb dead after gemm1
  unsigned short* vT    = WqkvT;   // alias: WqkvT dead after gemm1

  detect_dtype_k<<<1, 256, 0, stream>>>((const unsigned short*)x, flagp);
  cvt_all_k<<<2048, 256, 0, stream>>>(x, rel, bo, xb, relb, bob, flagp);
  transpose_all_k<<<4096, 256, 0, stream>>>(Wq, Wkv, Wo, WqkvT, nullptr, WoT, flagp);

  gemm_bt<<<dim3(24, 16), 256, 0, stream>>>(xb, WqkvT, 2048, 3072, 1024, 1,
                                            nullptr, q_ws, k_ws, v_ws, nullptr);
  transpose_v_k<<<dim3(16, 32), 256, 0, stream>>>(v_ws, vT);
  flash_attn<<<dim3(16, 32), 256, 0, stream>>>(q_ws, k_ws, vT, relb, ao);
  gemm_bt<<<dim3(8, 16), 256, 0, stream>>>(ao, WoT, 2048, 1024, 1024, 2,
                                           bob, nullptr, nullptr, nullptr, out);
}

// Round 5
// 215.606 us; speedup vs baseline: 1.3059x; 1.3059x over previous
//
#include <hip/hip_runtime.h>

typedef __bf16 bf16x8 __attribute__((ext_vector_type(8)));
typedef float f32x4 __attribute__((ext_vector_type(4)));

#define DEV __device__ __forceinline__

DEV unsigned short f2bf(float f) {
  union { float f; unsigned u; } x; x.f = f;
  unsigned r = x.u + 0x7FFFu + ((x.u >> 16) & 1u);  // RNE
  return (unsigned short)(r >> 16);
}
DEV float bf2f(unsigned short h) {
  union { unsigned u; float f; } x; x.u = ((unsigned)h) << 16;
  return x.f;
}

typedef __attribute__((address_space(3))) void* lds_vp;
typedef const __attribute__((address_space(1))) void* gbl_vp;
DEV void load_lds16(const unsigned short* gp, void* lp) {
  __builtin_amdgcn_global_load_lds((gbl_vp)(const void*)gp, (lds_vp)lp, 16, 0, 0);
}

// ---- dtype detector: f32 buffers read as bf16 show mantissa-noise exponents
__global__ void detect_dtype_k(const unsigned short* __restrict__ x,
                               int* __restrict__ flag) {
  __shared__ int cnt;
  if (threadIdx.x == 0) cnt = 0;
  __syncthreads();
  int c = 0;
  for (int i = threadIdx.x; i < 8192; i += 256) {
    unsigned e = (x[i] >> 7) & 0xFFu;
    c += (e >= 0xC0u) ? 1 : 0;
  }
  atomicAdd(&cnt, c);
  __syncthreads();
  if (threadIdx.x == 0) *flag = (cnt > 64) ? 1 : 0;
}

// ---- fused convert: x (2097152) | rel (65600) | bo (1024) -> bf16
__global__ void cvt_all_k(const void* __restrict__ xs, const void* __restrict__ rs,
                          const void* __restrict__ bs,
                          unsigned short* __restrict__ xd,
                          unsigned short* __restrict__ rd,
                          unsigned short* __restrict__ bd,
                          const int* __restrict__ flag) {
  const int f = *flag;
  const int NX = 2097152, NR = 65600, NB = 1024;
  for (int i = blockIdx.x * 256 + threadIdx.x; i < NX + NR + NB; i += gridDim.x * 256) {
    const void* src; unsigned short* dst; int j;
    if (i < NX)            { src = xs; dst = xd; j = i; }
    else if (i < NX + NR)  { src = rs; dst = rd; j = i - NX; }
    else                   { src = bs; dst = bd; j = i - NX - NR; }
    dst[j] = f ? f2bf(((const float*)src)[j]) : ((const unsigned short*)src)[j];
  }
}

// ---- fused transpose+convert of the three weights: dst[C][R] = src[R][C]
__global__ void transpose_all_k(const void* __restrict__ Wq, const void* __restrict__ Wkv,
                                const void* __restrict__ Wo,
                                unsigned short* __restrict__ dq,   // Wkv dst at +1048576
                                unsigned short* __restrict__ dwo,
                                const int* __restrict__ flag) {
  __shared__ unsigned short tile[32][33];
  const int f = *flag;
  int id = blockIdx.x;
  const void* src; unsigned short* dst; int R = 1024, C; int tx_t, ty_t;
  if (id < 1024)       { src = Wq;  dst = dq;            C = 1024; tx_t = id & 31;  ty_t = id >> 5; }
  else if (id < 3072)  { int l = id - 1024; src = Wkv; dst = dq + 1048576; C = 2048; tx_t = l & 63; ty_t = l >> 6; }
  else                 { int l = id - 3072; src = Wo;  dst = dwo;          C = 1024; tx_t = l & 31; ty_t = l >> 5; }
  const float* sf = (const float*)src;
  const unsigned short* su = (const unsigned short*)src;
  int c0 = tx_t * 32, r0 = ty_t * 32;
  int tx = threadIdx.x & 31, ty = threadIdx.x >> 5;  // 32x8
  #pragma unroll
  for (int i = 0; i < 4; ++i) {
    size_t idx = (size_t)(r0 + ty + i * 8) * C + c0 + tx;
    tile[ty + i * 8][tx] = f ? f2bf(sf[idx]) : su[idx];
  }
  __syncthreads();
  #pragma unroll
  for (int i = 0; i < 4; ++i)
    dst[(size_t)(c0 + ty + i * 8) * R + r0 + tx] = tile[tx][ty + i * 8];
}

// ---- per-head V transpose: v[bh][n][d] -> vT[bh][d][n]
__global__ __launch_bounds__(256)
void transpose_v_k(const unsigned short* __restrict__ v,
                   unsigned short* __restrict__ vt) {
  __shared__ __align__(16) unsigned short st[64][68];
  const int bh = blockIdx.y, n0 = blockIdx.x * 64;
  const unsigned short* vp = v + (size_t)bh * 1024 * 64;
  unsigned short* tp = vt + (size_t)bh * 64 * 1024;
  #pragma unroll
  for (int cc = 0; cc < 2; ++cc) {
    int ci = threadIdx.x + cc * 256;
    int row = ci >> 3, dc = (ci & 7) * 8;
    *(uint4*)&st[row][dc] = *(const uint4*)&vp[(size_t)(n0 + row) * 64 + dc];
  }
  __syncthreads();
  #pragma unroll
  for (int cc = 0; cc < 2; ++cc) {
    int ci = threadIdx.x + cc * 256;
    int d = ci >> 3, nc = (ci & 7) * 8;
    union { uint4 v; unsigned short us[8]; } t;
    #pragma unroll
    for (int e = 0; e < 8; ++e) t.us[e] = st[nc + e][d];
    *(uint4*)&tp[(size_t)d * 1024 + n0 + nc] = t.v;
  }
}

// ---------------- GEMM C = A @ Bt^T  (A[M][K], Bt[N][K], bf16) -------------
__global__ __launch_bounds__(256)
void gemm_bt(const unsigned short* __restrict__ A,
             const unsigned short* __restrict__ Bt,
             int M, int N, int K, int mode,
             const unsigned short* __restrict__ bias,
             unsigned short* __restrict__ o0,
             unsigned short* __restrict__ o1,
             unsigned short* __restrict__ o2,
             float* __restrict__ fo) {
  __shared__ __align__(16) unsigned short As[128][32];
  __shared__ __align__(16) unsigned short Bs[128][32];
  const int tid  = threadIdx.x;
  const int lane = tid & 63, wave = tid >> 6;
  const int q15  = lane & 15, quad = lane >> 4;
  const int wr = wave >> 1, wc = wave & 1;
  const int m0 = blockIdx.y * 128, n0 = blockIdx.x * 128;

  const int lrow = lane >> 2, lkc = (lane & 3) * 8;

  f32x4 acc[4][4] = {};

  for (int k0 = 0; k0 < K; k0 += 32) {
    __syncthreads();
    #pragma unroll
    for (int t = 0; t < 2; ++t) {
      int r0 = wave * 32 + t * 16;
      load_lds16(&A[(size_t)(m0 + r0 + lrow) * K + k0 + lkc], &As[r0][0]);
      load_lds16(&Bt[(size_t)(n0 + r0 + lrow) * K + k0 + lkc], &Bs[r0][0]);
    }
    __syncthreads();
    bf16x8 af[4], bfr[4];
    #pragma unroll
    for (int i = 0; i < 4; ++i) {
      af[i]  = *(const bf16x8*)&As[wr * 64 + i * 16 + q15][quad * 8];
      bfr[i] = *(const bf16x8*)&Bs[wc * 64 + i * 16 + q15][quad * 8];
    }
    #pragma unroll
    for (int i = 0; i < 4; ++i)
      #pragma unroll
      for (int j = 0; j < 4; ++j)
        acc[i][j] = __builtin_amdgcn_mfma_f32_16x16x32_bf16(af[i], bfr[j], acc[i][j], 0, 0, 0);
  }

  #pragma unroll
  for (int i = 0; i < 4; ++i)
    #pragma unroll
    for (int j = 0; j < 4; ++j)
      #pragma unroll
      for (int r = 0; r < 4; ++r) {
        int row = m0 + wr * 64 + i * 16 + quad * 4 + r;
        int col = n0 + wc * 64 + j * 16 + q15;
        float v = acc[i][j][r];
        if (mode == 2) {
          fo[(size_t)row * N + col] = v + bf2f(bias[col]);
        } else {
          int b = row >> 10, nn = row & 1023;
          unsigned short* dst; int c = col;
          if (col < 1024)      { dst = o0; }
          else if (col < 2048) { dst = o1; c = col - 1024; }
          else                 { dst = o2; c = col - 2048; }
          int h = c >> 6, dd = c & 63;
          dst[((size_t)(b * 16 + h) * 1024 + nn) * 64 + dd] = f2bf(v);
        }
      }
}

// ---- swizzled tile staging: [64 rows][64 shorts] tiles, chunk ^= row&7 ----
// lane c of an issue covers row r0+t*8+(c>>3), physical chunk c&7.
DEV void stage16(const unsigned short* gbase, size_t gstride,
                 unsigned short* lbase, int r0, int lane) {
  #pragma unroll
  for (int t = 0; t < 2; ++t) {
    int r = r0 + t * 8 + (lane >> 3);
    int lc = (lane & 7) ^ (r & 7);
    load_lds16(&gbase[(size_t)r * gstride + lc * 8], &lbase[(size_t)(r0 + t * 8) * 64]);
  }
}
DEV bf16x8 read_swz(const unsigned short* buf, int row, int lc) {
  int pc = lc ^ (row & 7);
  return *(const bf16x8*)&buf[row * 64 + pc * 8];
}

// ---------------- flash attention: LDS-staged K/V^T, double-buffered -------
// grid (x=bh 32, y=i-tile 16) -> block id % 8 == bh % 8 (XCD L2 locality).
// 4 waves x 16 Q-rows; j-tiles of 64; 1 barrier/iter; swizzled staging.
__global__ __launch_bounds__(256)
void flash_attn(const unsigned short* __restrict__ q_ws,
                const unsigned short* __restrict__ k_ws,
                const unsigned short* __restrict__ vt_ws,  // [bh][64][1024]
                const unsigned short* __restrict__ rel,    // [1025][64]
                unsigned short* __restrict__ ao) {         // [2048][1024]
  __shared__ __align__(16) unsigned short Kbuf[2][64 * 64];  // swizzled
  __shared__ __align__(16) unsigned short Vbuf[2][64 * 64];  // swizzled (V^T rows=d)
  __shared__ __align__(16) float T_lds[4][16][84];
  __shared__ __align__(16) unsigned short P_lds[4][16][72];

  const int tid  = threadIdx.x;
  const int lane = tid & 63, w = tid >> 6;
  const int q15  = lane & 15, quad = lane >> 4;
  const int bh = blockIdx.x;
  const int ib = blockIdx.y * 64 + w * 16;

  const unsigned short* qp = q_ws  + (size_t)bh * 1024 * 64;
  const unsigned short* kp = k_ws  + (size_t)bh * 1024 * 64;
  const unsigned short* tp = vt_ws + (size_t)bh * 64 * 1024;

  // Q strip, A-layout, pre-scaled by 0.125 (exact exponent shift)
  bf16x8 aq[2];
  #pragma unroll
  for (int ks = 0; ks < 2; ++ks) {
    const unsigned short* qrow = &qp[(size_t)(ib + q15) * 64 + ks * 32 + quad * 8];
    #pragma unroll
    for (int e = 0; e < 8; ++e)
      ((unsigned short*)&aq[ks])[e] = f2bf(bf2f(qrow[e]) * 0.125f);
  }

  f32x4 o[4] = {};
  float m_i[4], l_i[4];
  #pragma unroll
  for (int r = 0; r < 4; ++r) { m_i[r] = -60000.f; l_i[r] = 0.f; }

  // prologue: stage tile 0 (each wave stages its 16-row quarter)
  stage16(kp, 64, &Kbuf[0][0], w * 16, lane);
  stage16(tp, 1024, &Vbuf[0][0], w * 16, lane);

  #pragma unroll 2
  for (int jt = 0; jt < 16; ++jt) {
    const int j0 = jt * 64, cur = jt & 1;
    __syncthreads();  // staging of buf[cur] complete; prev iter's readers done
    if (jt + 1 < 16) {
      stage16(kp + (size_t)(j0 + 64) * 64, 64, &Kbuf[cur ^ 1][0], w * 16, lane);
      stage16(tp + (j0 + 64), 1024, &Vbuf[cur ^ 1][0], w * 16, lane);
    }

    // Q K^T from swizzled LDS
    f32x4 accS[4] = {};
    #pragma unroll
    for (int ks = 0; ks < 2; ++ks)
      #pragma unroll
      for (int cb = 0; cb < 4; ++cb) {
        bf16x8 bk = read_swz(&Kbuf[cur][0], cb * 16 + q15, ks * 4 + quad);
        accS[cb] = __builtin_amdgcn_mfma_f32_16x16x32_bf16(aq[ks], bk, accS[cb], 0, 0, 0);
      }
    // positional band T[16][80] (rel is L2-hot everywhere)
    int tb = ib - j0 + 512 - 63;
    f32x4 accT[5] = {};
    #pragma unroll
    for (int ks = 0; ks < 2; ++ks)
      #pragma unroll
      for (int ub = 0; ub < 5; ++ub) {
        int trow = tb + ub * 16 + q15;
        trow = trow < 0 ? 0 : (trow > 1024 ? 1024 : trow);
        bf16x8 br = *(const bf16x8*)&rel[(size_t)trow * 64 + ks * 32 + quad * 8];
        accT[ub] = __builtin_amdgcn_mfma_f32_16x16x32_bf16(aq[ks], br, accT[ub], 0, 0, 0);
      }
    #pragma unroll
    for (int ub = 0; ub < 5; ++ub)
      #pragma unroll
      for (int r = 0; r < 4; ++r)
        T_lds[w][quad * 4 + r][ub * 16 + q15] = accT[ub][r];

    float s[4][4];
    #pragma unroll
    for (int cb = 0; cb < 4; ++cb)
      #pragma unroll
      for (int r = 0; r < 4; ++r) {
        int dl = quad * 4 + r, dj = cb * 16 + q15;
        s[cb][r] = accS[cb][r] + T_lds[w][dl][63 + dl - dj];
      }
    #pragma unroll
    for (int r = 0; r < 4; ++r) {
      float mx = fmaxf(fmaxf(s[0][r], s[1][r]), fmaxf(s[2][r], s[3][r]));
      #pragma unroll
      for (int off = 1; off < 16; off <<= 1)
        mx = fmaxf(mx, __shfl_xor(mx, off, 64));
      float mnew = fmaxf(m_i[r], mx);
      float alpha = exp2f(fmaxf((m_i[r] - mnew) * 1.44269504f, -126.f));
      m_i[r] = mnew;
      float pr[4], sum = 0.f;
      #pragma unroll
      for (int cb = 0; cb < 4; ++cb) {
        pr[cb] = exp2f(fmaxf((s[cb][r] - mnew) * 1.44269504f, -126.f));
        sum += pr[cb];
      }
      #pragma unroll
      for (int off = 1; off < 16; off <<= 1)
        sum += __shfl_xor(sum, off, 64);
      l_i[r] = l_i[r] * alpha + sum;
      #pragma unroll
      for (int db = 0; db < 4; ++db) o[db][r] *= alpha;
      #pragma unroll
      for (int cb = 0; cb < 4; ++cb)
        P_lds[w][quad * 4 + r][cb * 16 + q15] = f2bf(pr[cb]);
    }

    // O += P @ V   (V^T rows = d, swizzled LDS)
    #pragma unroll
    for (int ks = 0; ks < 2; ++ks) {
      bf16x8 ap = *(const bf16x8*)&P_lds[w][q15][ks * 32 + quad * 8];
      #pragma unroll
      for (int db = 0; db < 4; ++db) {
        bf16x8 bv = read_swz(&Vbuf[cur][0], db * 16 + q15, ks * 4 + quad);
        o[db] = __builtin_amdgcn_mfma_f32_16x16x32_bf16(ap, bv, o[db], 0, 0, 0);
      }
    }
  }

  int b = bh >> 4, h = bh & 15;
  #pragma unroll
  for (int db = 0; db < 4; ++db)
    #pragma unroll
    for (int r = 0; r < 4; ++r) {
      int row = ib + quad * 4 + r;
      float val = o[db][r] / l_i[r];
      ao[((size_t)(b * 1024 + row)) * 1024 + h * 64 + db * 16 + q15] = f2bf(val);
    }
}

// ---------------------------------------------------------------------------
extern "C" void kernel_launch(void* const* d_in, const int* in_sizes, int n_in,
                              void* d_out, int out_size, void* d_ws, size_t ws_size,
                              hipStream_t stream) {
  (void)in_sizes; (void)n_in; (void)out_size; (void)ws_size;
  const void* x   = d_in[0];
  const void* Wq  = d_in[1];
  const void* Wkv = d_in[2];
  const void* Wo  = d_in[3];
  const void* bo  = d_in[4];
  const void* rel = d_in[5];
  float* out = (float*)d_out;

  unsigned short* ws = (unsigned short*)d_ws;
  unsigned short* xb    = ws;                     // 2,097,152
  unsigned short* WqkvT = xb    + 2097152;        // 3,145,728 (vT aliases later)
  unsigned short* WoT   = WqkvT + 3145728;        // 1,048,576
  unsigned short* relb  = WoT   + 1048576;        // 65,664 reserved
  unsigned short* bob   = relb  + 65664;          // 1024
  int*            flagp = (int*)(bob + 1024);     // 64 reserved
  unsigned short* q_ws  = bob   + 1024 + 64;
  unsigned short* k_ws  = q_ws  + 2097152;
  unsigned short* v_ws  = k_ws  + 2097152;
  unsigned short* ao    = xb;      // alias: xb dead after gemm1
  unsigned short* vT    = WqkvT;   // alias: WqkvT dead after gemm1

  detect_dtype_k<<<1, 256, 0, stream>>>((const unsigned short*)x, flagp);
  cvt_all_k<<<2048, 256, 0, stream>>>(x, rel, bo, xb, relb, bob, flagp);
  transpose_all_k<<<4096, 256, 0, stream>>>(Wq, Wkv, Wo, WqkvT, WoT, flagp);

  gemm_bt<<<dim3(24, 16), 256, 0, stream>>>(xb, WqkvT, 2048, 3072, 1024, 1,
                                            nullptr, q_ws, k_ws, v_ws, nullptr);
  transpose_v_k<<<dim3(16, 32), 256, 0, stream>>>(v_ws, vT);
  flash_attn<<<dim3(32, 16), 256, 0, stream>>>(q_ws, k_ws, vT, relb, ao);
  gemm_bt<<<dim3(8, 16), 256, 0, stream>>>(ao, WoT, 2048, 1024, 1024, 2,
                                           bob, nullptr, nullptr, nullptr, out);
}

// Round 6
// 196.549 us; speedup vs baseline: 1.4325x; 1.0970x over previous
//
#include <hip/hip_runtime.h>

typedef __bf16 bf16x8 __attribute__((ext_vector_type(8)));
typedef float f32x4 __attribute__((ext_vector_type(4)));

#define DEV __device__ __forceinline__

DEV unsigned short f2bf(float f) {
  union { float f; unsigned u; } x; x.f = f;
  unsigned r = x.u + 0x7FFFu + ((x.u >> 16) & 1u);  // RNE
  return (unsigned short)(r >> 16);
}
DEV float bf2f(unsigned short h) {
  union { unsigned u; float f; } x; x.u = ((unsigned)h) << 16;
  return x.f;
}

typedef __attribute__((address_space(3))) void* lds_vp;
typedef const __attribute__((address_space(1))) void* gbl_vp;
DEV void load_lds16(const unsigned short* gp, void* lp) {
  __builtin_amdgcn_global_load_lds((gbl_vp)(const void*)gp, (lds_vp)lp, 16, 0, 0);
}

// ---- fused ingest (inputs are f32 — proven rounds 1-3):
// blocks [0,2048): x -> xb ; [2048,2113): rel ; 2113: bo ;
// [2114, 6210): 32x32 transpose tiles of Wq|Wkv|Wo -> WqkvT / WoT
__global__ __launch_bounds__(256)
void prep_k(const float* __restrict__ x, const float* __restrict__ rel,
            const float* __restrict__ bo, const float* __restrict__ Wq,
            const float* __restrict__ Wkv, const float* __restrict__ Wo,
            unsigned short* __restrict__ xb, unsigned short* __restrict__ relb,
            unsigned short* __restrict__ bob, unsigned short* __restrict__ WqkvT,
            unsigned short* __restrict__ WoT) {
  __shared__ unsigned short tile[32][33];
  const int bid = blockIdx.x, tid = threadIdx.x;
  if (bid < 2114) {
    const float* src; unsigned short* dst; long base; long n;
    if (bid < 2048)      { src = x;   dst = xb;   base = (long)bid * 1024;          n = 2097152; }
    else if (bid < 2113) { src = rel; dst = relb; base = (long)(bid - 2048) * 1024; n = 65600; }
    else                 { src = bo;  dst = bob;  base = 0;                          n = 1024; }
    long i = base + tid * 4;
    if (i < n) {
      float4 v = *(const float4*)&src[i];
      unsigned long long u = (unsigned long long)f2bf(v.x)
                           | ((unsigned long long)f2bf(v.y) << 16)
                           | ((unsigned long long)f2bf(v.z) << 32)
                           | ((unsigned long long)f2bf(v.w) << 48);
      *(unsigned long long*)&dst[i] = u;
    }
  } else {
    int id = bid - 2114;
    const float* src; unsigned short* dst; const int R = 1024; int C, txt, tyt;
    if (id < 1024)      { src = Wq;  dst = WqkvT;           C = 1024; txt = id & 31; tyt = id >> 5; }
    else if (id < 3072) { int l = id - 1024; src = Wkv; dst = WqkvT + 1048576; C = 2048; txt = l & 63; tyt = l >> 6; }
    else                { int l = id - 3072; src = Wo;  dst = WoT;             C = 1024; txt = l & 31; tyt = l >> 5; }
    int c0 = txt * 32, r0 = tyt * 32;
    int tx = tid & 31, ty = tid >> 5;  // 32x8
    #pragma unroll
    for (int i = 0; i < 4; ++i)
      tile[ty + i * 8][tx] = f2bf(src[(size_t)(r0 + ty + i * 8) * C + c0 + tx]);
    __syncthreads();
    #pragma unroll
    for (int i = 0; i < 4; ++i)
      dst[(size_t)(c0 + ty + i * 8) * R + r0 + tx] = tile[tx][ty + i * 8];
  }
}

// ---------------- GEMM C = A @ Bt^T  (A[M][K], Bt[N][K], bf16) -------------
// 128x128 tile, BK=32, global_load_lds staging (m97 structure).
// mode 1: cols -> q(*0.125, [b,h,n,d]) | k([b,h,n,d]) | v -> vT[b,h,d,n]
// mode 2: +bias, f32 row-major out.
__global__ __launch_bounds__(256)
void gemm_bt(const unsigned short* __restrict__ A,
             const unsigned short* __restrict__ Bt,
             int M, int N, int K, int mode,
             const unsigned short* __restrict__ bias,
             unsigned short* __restrict__ o0,
             unsigned short* __restrict__ o1,
             unsigned short* __restrict__ o2,
             float* __restrict__ fo) {
  __shared__ __align__(16) unsigned short As[128][32];
  __shared__ __align__(16) unsigned short Bs[128][32];
  const int tid  = threadIdx.x;
  const int lane = tid & 63, wave = tid >> 6;
  const int q15  = lane & 15, quad = lane >> 4;
  const int wr = wave >> 1, wc = wave & 1;
  const int m0 = blockIdx.y * 128, n0 = blockIdx.x * 128;

  const int lrow = lane >> 2, lkc = (lane & 3) * 8;

  f32x4 acc[4][4] = {};

  for (int k0 = 0; k0 < K; k0 += 32) {
    __syncthreads();
    #pragma unroll
    for (int t = 0; t < 2; ++t) {
      int r0 = wave * 32 + t * 16;
      load_lds16(&A[(size_t)(m0 + r0 + lrow) * K + k0 + lkc], &As[r0][0]);
      load_lds16(&Bt[(size_t)(n0 + r0 + lrow) * K + k0 + lkc], &Bs[r0][0]);
    }
    __syncthreads();
    bf16x8 af[4], bfr[4];
    #pragma unroll
    for (int i = 0; i < 4; ++i) {
      af[i]  = *(const bf16x8*)&As[wr * 64 + i * 16 + q15][quad * 8];
      bfr[i] = *(const bf16x8*)&Bs[wc * 64 + i * 16 + q15][quad * 8];
    }
    #pragma unroll
    for (int i = 0; i < 4; ++i)
      #pragma unroll
      for (int j = 0; j < 4; ++j)
        acc[i][j] = __builtin_amdgcn_mfma_f32_16x16x32_bf16(af[i], bfr[j], acc[i][j], 0, 0, 0);
  }

  #pragma unroll
  for (int i = 0; i < 4; ++i)
    #pragma unroll
    for (int j = 0; j < 4; ++j)
      #pragma unroll
      for (int r = 0; r < 4; ++r) {
        int row = m0 + wr * 64 + i * 16 + quad * 4 + r;
        int col = n0 + wc * 64 + j * 16 + q15;
        float v = acc[i][j][r];
        if (mode == 2) {
          fo[(size_t)row * N + col] = v + bf2f(bias[col]);
        } else {
          int b = row >> 10, nn = row & 1023;
          if (col < 1024) {
            int h = col >> 6, dd = col & 63;
            o0[((size_t)(b * 16 + h) * 1024 + nn) * 64 + dd] = f2bf(v * 0.125f);
          } else if (col < 2048) {
            int c = col - 1024, h = c >> 6, dd = c & 63;
            o1[((size_t)(b * 16 + h) * 1024 + nn) * 64 + dd] = f2bf(v);
          } else {
            int c = col - 2048, h = c >> 6, dd = c & 63;
            o2[((size_t)(b * 16 + h) * 64 + dd) * 1024 + nn] = f2bf(v);  // vT
          }
        }
      }
}

// ---- swizzled tile staging: [64 rows][64 shorts] tiles, chunk ^= row&7 ----
DEV void stage16(const unsigned short* gbase, size_t gstride,
                 unsigned short* lbase, int r0, int lane) {
  #pragma unroll
  for (int t = 0; t < 2; ++t) {
    int r = r0 + t * 8 + (lane >> 3);
    int lc = (lane & 7) ^ (r & 7);
    load_lds16(&gbase[(size_t)r * gstride + lc * 8], &lbase[(size_t)(r0 + t * 8) * 64]);
  }
}
DEV bf16x8 read_swz(const unsigned short* buf, int row, int lc) {
  int pc = lc ^ (row & 7);
  return *(const bf16x8*)&buf[row * 64 + pc * 8];
}

// ---------------- flash attention: fixed-offset softmax --------------------
// p = exp2(logit*log2e - 64): softmax ratios preserved, no running max,
// no o-rescale chain; l accumulated per-lane, reduced once at the end.
// grid (x=bh 32 -> XCD locality, y=i-tile 16); 4 waves x 16 Q-rows.
__global__ __launch_bounds__(256)
void flash_attn(const unsigned short* __restrict__ q_ws,   // pre-scaled by 0.125
                const unsigned short* __restrict__ k_ws,
                const unsigned short* __restrict__ vt_ws,  // [bh][64][1024]
                const unsigned short* __restrict__ rel,    // [1025][64] bf16
                unsigned short* __restrict__ ao) {         // [2048][1024]
  __shared__ __align__(16) unsigned short Kbuf[2][64 * 64];
  __shared__ __align__(16) unsigned short Vbuf[2][64 * 64];
  __shared__ __align__(16) unsigned short T_lds[4][16][92];  // bf16, stride 92
  __shared__ __align__(16) unsigned short P_lds[4][16][76];  // stride 76

  const int tid  = threadIdx.x;
  const int lane = tid & 63, w = tid >> 6;
  const int q15  = lane & 15, quad = lane >> 4;
  const int bh = blockIdx.x;
  const int ib = blockIdx.y * 64 + w * 16;

  const unsigned short* qp = q_ws  + (size_t)bh * 1024 * 64;
  const unsigned short* kp = k_ws  + (size_t)bh * 1024 * 64;
  const unsigned short* tp = vt_ws + (size_t)bh * 64 * 1024;

  bf16x8 aq[2];
  #pragma unroll
  for (int ks = 0; ks < 2; ++ks)
    aq[ks] = *(const bf16x8*)&qp[(size_t)(ib + q15) * 64 + ks * 32 + quad * 8];

  f32x4 o[4] = {};
  float l_i[4] = {0.f, 0.f, 0.f, 0.f};

  stage16(kp, 64, &Kbuf[0][0], w * 16, lane);
  stage16(tp, 1024, &Vbuf[0][0], w * 16, lane);

  #pragma unroll 2
  for (int jt = 0; jt < 16; ++jt) {
    const int j0 = jt * 64, cur = jt & 1;
    __syncthreads();
    if (jt + 1 < 16) {
      stage16(kp + (size_t)(j0 + 64) * 64, 64, &Kbuf[cur ^ 1][0], w * 16, lane);
      stage16(tp + (j0 + 64), 1024, &Vbuf[cur ^ 1][0], w * 16, lane);
    }

    // Q K^T
    f32x4 accS[4] = {};
    #pragma unroll
    for (int ks = 0; ks < 2; ++ks)
      #pragma unroll
      for (int cb = 0; cb < 4; ++cb) {
        bf16x8 bk = read_swz(&Kbuf[cur][0], cb * 16 + q15, ks * 4 + quad);
        accS[cb] = __builtin_amdgcn_mfma_f32_16x16x32_bf16(aq[ks], bk, accS[cb], 0, 0, 0);
      }
    // positional band T[16][80]
    int tb = ib - j0 + 512 - 63;
    f32x4 accT[5] = {};
    #pragma unroll
    for (int ks = 0; ks < 2; ++ks)
      #pragma unroll
      for (int ub = 0; ub < 5; ++ub) {
        int trow = tb + ub * 16 + q15;
        trow = trow < 0 ? 0 : (trow > 1024 ? 1024 : trow);
        bf16x8 br = *(const bf16x8*)&rel[(size_t)trow * 64 + ks * 32 + quad * 8];
        accT[ub] = __builtin_amdgcn_mfma_f32_16x16x32_bf16(aq[ks], br, accT[ub], 0, 0, 0);
      }
    #pragma unroll
    for (int ub = 0; ub < 5; ++ub)
      #pragma unroll
      for (int r = 0; r < 4; ++r)
        T_lds[w][quad * 4 + r][ub * 16 + q15] = f2bf(accT[ub][r]);

    // p = exp2(logit*log2e - 64); accumulate l per-lane; stage P
    #pragma unroll
    for (int r = 0; r < 4; ++r) {
      const int dl = quad * 4 + r;
      #pragma unroll
      for (int cb = 0; cb < 4; ++cb) {
        int dj = cb * 16 + q15;
        float s = accS[cb][r] + bf2f(T_lds[w][dl][63 + dl - dj]);
        float p = exp2f(s * 1.44269504f - 64.f);
        l_i[r] += p;
        P_lds[w][dl][cb * 16 + q15] = f2bf(p);
      }
    }

    // O += P @ V
    #pragma unroll
    for (int ks = 0; ks < 2; ++ks) {
      bf16x8 ap = *(const bf16x8*)&P_lds[w][q15][ks * 32 + quad * 8];
      #pragma unroll
      for (int db = 0; db < 4; ++db) {
        bf16x8 bv = read_swz(&Vbuf[cur][0], db * 16 + q15, ks * 4 + quad);
        o[db] = __builtin_amdgcn_mfma_f32_16x16x32_bf16(ap, bv, o[db], 0, 0, 0);
      }
    }
  }

  // one l-reduction at the end (16-lane butterfly within quad groups)
  #pragma unroll
  for (int r = 0; r < 4; ++r) {
    #pragma unroll
    for (int off = 1; off < 16; off <<= 1)
      l_i[r] += __shfl_xor(l_i[r], off, 64);
    l_i[r] += 1e-30f;
  }

  int b = bh >> 4, h = bh & 15;
  #pragma unroll
  for (int db = 0; db < 4; ++db)
    #pragma unroll
    for (int r = 0; r < 4; ++r) {
      int row = ib + quad * 4 + r;
      float val = o[db][r] / l_i[r];
      ao[((size_t)(b * 1024 + row)) * 1024 + h * 64 + db * 16 + q15] = f2bf(val);
    }
}

// ---------------------------------------------------------------------------
extern "C" void kernel_launch(void* const* d_in, const int* in_sizes, int n_in,
                              void* d_out, int out_size, void* d_ws, size_t ws_size,
                              hipStream_t stream) {
  (void)in_sizes; (void)n_in; (void)out_size; (void)ws_size;
  const float* x   = (const float*)d_in[0];
  const float* Wq  = (const float*)d_in[1];
  const float* Wkv = (const float*)d_in[2];
  const float* Wo  = (const float*)d_in[3];
  const float* bo  = (const float*)d_in[4];
  const float* rel = (const float*)d_in[5];
  float* out = (float*)d_out;

  unsigned short* ws = (unsigned short*)d_ws;
  unsigned short* xb    = ws;                     // 2,097,152
  unsigned short* WqkvT = xb    + 2097152;        // 3,145,728
  unsigned short* WoT   = WqkvT + 3145728;        // 1,048,576
  unsigned short* relb  = WoT   + 1048576;        // 65,664 reserved
  unsigned short* bob   = relb  + 65664;          // 1024
  unsigned short* q_ws  = bob   + 1024;           // 2,097,152 each
  unsigned short* k_ws  = q_ws  + 2097152;
  unsigned short* vT    = k_ws  + 2097152;        // [bh][d][n]
  unsigned short* ao    = xb;                     // alias: xb dead after gemm1

  prep_k<<<6210, 256, 0, stream>>>(x, rel, bo, Wq, Wkv, Wo,
                                   xb, relb, bob, WqkvT, WoT);
  gemm_bt<<<dim3(24, 16), 256, 0, stream>>>(xb, WqkvT, 2048, 3072, 1024, 1,
                                            nullptr, q_ws, k_ws, vT, nullptr);
  flash_attn<<<dim3(32, 16), 256, 0, stream>>>(q_ws, k_ws, vT, relb, ao);
  gemm_bt<<<dim3(8, 16), 256, 0, stream>>>(ao, WoT, 2048, 1024, 1024, 2,
                                           bob, nullptr, nullptr, nullptr, out);
}

// Round 7
// 184.444 us; speedup vs baseline: 1.5265x; 1.0656x over previous
//
#include <hip/hip_runtime.h>

typedef __bf16 bf16x8 __attribute__((ext_vector_type(8)));
typedef float f32x4 __attribute__((ext_vector_type(4)));

#define DEV __device__ __forceinline__

DEV unsigned short f2bf(float f) {
  union { float f; unsigned u; } x; x.f = f;
  unsigned r = x.u + 0x7FFFu + ((x.u >> 16) & 1u);  // RNE
  return (unsigned short)(r >> 16);
}
DEV float bf2f(unsigned short h) {
  union { unsigned u; float f; } x; x.u = ((unsigned)h) << 16;
  return x.f;
}

typedef __attribute__((address_space(3))) void* lds_vp;
typedef const __attribute__((address_space(1))) void* gbl_vp;
DEV void load_lds16(const unsigned short* gp, void* lp) {
  __builtin_amdgcn_global_load_lds((gbl_vp)(const void*)gp, (lds_vp)lp, 16, 0, 0);
}

// ---- fused ingest (inputs f32): convert x/rel/bo, transpose Wq|Wkv|Wo -----
__global__ __launch_bounds__(256)
void prep_k(const float* __restrict__ x, const float* __restrict__ rel,
            const float* __restrict__ bo, const float* __restrict__ Wq,
            const float* __restrict__ Wkv, const float* __restrict__ Wo,
            unsigned short* __restrict__ xb, unsigned short* __restrict__ relb,
            unsigned short* __restrict__ bob, unsigned short* __restrict__ WqkvT,
            unsigned short* __restrict__ WoT) {
  __shared__ unsigned short tile[32][33];
  const int bid = blockIdx.x, tid = threadIdx.x;
  if (bid < 2114) {
    const float* src; unsigned short* dst; long base; long n;
    if (bid < 2048)      { src = x;   dst = xb;   base = (long)bid * 1024;          n = 2097152; }
    else if (bid < 2113) { src = rel; dst = relb; base = (long)(bid - 2048) * 1024; n = 65600; }
    else                 { src = bo;  dst = bob;  base = 0;                          n = 1024; }
    long i = base + tid * 4;
    if (i < n) {
      float4 v = *(const float4*)&src[i];
      unsigned long long u = (unsigned long long)f2bf(v.x)
                           | ((unsigned long long)f2bf(v.y) << 16)
                           | ((unsigned long long)f2bf(v.z) << 32)
                           | ((unsigned long long)f2bf(v.w) << 48);
      *(unsigned long long*)&dst[i] = u;
    }
  } else {
    int id = bid - 2114;
    const float* src; unsigned short* dst; const int R = 1024; int C, txt, tyt;
    if (id < 1024)      { src = Wq;  dst = WqkvT;           C = 1024; txt = id & 31; tyt = id >> 5; }
    else if (id < 3072) { int l = id - 1024; src = Wkv; dst = WqkvT + 1048576; C = 2048; txt = l & 63; tyt = l >> 6; }
    else                { int l = id - 3072; src = Wo;  dst = WoT;             C = 1024; txt = l & 31; tyt = l >> 5; }
    int c0 = txt * 32, r0 = tyt * 32;
    int tx = tid & 31, ty = tid >> 5;
    #pragma unroll
    for (int i = 0; i < 4; ++i)
      tile[ty + i * 8][tx] = f2bf(src[(size_t)(r0 + ty + i * 8) * C + c0 + tx]);
    __syncthreads();
    #pragma unroll
    for (int i = 0; i < 4; ++i)
      dst[(size_t)(c0 + ty + i * 8) * R + r0 + tx] = tile[tx][ty + i * 8];
  }
}

// ---------------- GEMM qkv = x @ WqkvT^T; q*0.125; all [b,h,n,d] coalesced --
__global__ __launch_bounds__(256)
void gemm_qkv(const unsigned short* __restrict__ A,
              const unsigned short* __restrict__ Bt,
              unsigned short* __restrict__ o0,   // q
              unsigned short* __restrict__ o1,   // k
              unsigned short* __restrict__ o2) { // v row-major
  __shared__ __align__(16) unsigned short As[128][32];
  __shared__ __align__(16) unsigned short Bs[128][32];
  const int tid  = threadIdx.x;
  const int lane = tid & 63, wave = tid >> 6;
  const int q15  = lane & 15, quad = lane >> 4;
  const int wr = wave >> 1, wc = wave & 1;
  const int m0 = blockIdx.y * 128, n0 = blockIdx.x * 128;
  const int K = 1024;
  const int lrow = lane >> 2, lkc = (lane & 3) * 8;

  f32x4 acc[4][4] = {};
  for (int k0 = 0; k0 < K; k0 += 32) {
    __syncthreads();
    #pragma unroll
    for (int t = 0; t < 2; ++t) {
      int r0 = wave * 32 + t * 16;
      load_lds16(&A[(size_t)(m0 + r0 + lrow) * K + k0 + lkc], &As[r0][0]);
      load_lds16(&Bt[(size_t)(n0 + r0 + lrow) * K + k0 + lkc], &Bs[r0][0]);
    }
    __syncthreads();
    bf16x8 af[4], bfr[4];
    #pragma unroll
    for (int i = 0; i < 4; ++i) {
      af[i]  = *(const bf16x8*)&As[wr * 64 + i * 16 + q15][quad * 8];
      bfr[i] = *(const bf16x8*)&Bs[wc * 64 + i * 16 + q15][quad * 8];
    }
    #pragma unroll
    for (int i = 0; i < 4; ++i)
      #pragma unroll
      for (int j = 0; j < 4; ++j)
        acc[i][j] = __builtin_amdgcn_mfma_f32_16x16x32_bf16(af[i], bfr[j], acc[i][j], 0, 0, 0);
  }
  #pragma unroll
  for (int i = 0; i < 4; ++i)
    #pragma unroll
    for (int j = 0; j < 4; ++j)
      #pragma unroll
      for (int r = 0; r < 4; ++r) {
        int row = m0 + wr * 64 + i * 16 + quad * 4 + r;
        int col = n0 + wc * 64 + j * 16 + q15;
        float v = acc[i][j][r];
        int b = row >> 10, nn = row & 1023;
        unsigned short* dst; int c = col; float sc = 1.f;
        if (col < 1024)      { dst = o0; sc = 0.125f; }
        else if (col < 2048) { dst = o1; c = col - 1024; }
        else                 { dst = o2; c = col - 2048; }
        int h = c >> 6, dd = c & 63;
        dst[((size_t)(b * 16 + h) * 1024 + nn) * 64 + dd] = f2bf(v * sc);
      }
}

// ---- per-head V transpose: v[bh][n][d] -> vT[bh][d][n]
__global__ __launch_bounds__(256)
void transpose_v_k(const unsigned short* __restrict__ v,
                   unsigned short* __restrict__ vt) {
  __shared__ __align__(16) unsigned short st[64][68];
  const int bh = blockIdx.y, n0 = blockIdx.x * 64;
  const unsigned short* vp = v + (size_t)bh * 1024 * 64;
  unsigned short* tp = vt + (size_t)bh * 64 * 1024;
  #pragma unroll
  for (int cc = 0; cc < 2; ++cc) {
    int ci = threadIdx.x + cc * 256;
    int row = ci >> 3, dc = (ci & 7) * 8;
    *(uint4*)&st[row][dc] = *(const uint4*)&vp[(size_t)(n0 + row) * 64 + dc];
  }
  __syncthreads();
  #pragma unroll
  for (int cc = 0; cc < 2; ++cc) {
    int ci = threadIdx.x + cc * 256;
    int d = ci >> 3, nc = (ci & 7) * 8;
    union { uint4 v; unsigned short us[8]; } t;
    #pragma unroll
    for (int e = 0; e < 8; ++e) t.us[e] = st[nc + e][d];
    *(uint4*)&tp[(size_t)d * 1024 + n0 + nc] = t.v;
  }
}

// ---- swizzled tile staging: [64 rows][64 shorts], chunk ^= row&7 ----------
DEV void stage16(const unsigned short* gbase, size_t gstride,
                 unsigned short* lbase, int r0, int lane) {
  #pragma unroll
  for (int t = 0; t < 2; ++t) {
    int r = r0 + t * 8 + (lane >> 3);
    int lc = (lane & 7) ^ (r & 7);
    load_lds16(&gbase[(size_t)r * gstride + lc * 8], &lbase[(size_t)(r0 + t * 8) * 64]);
  }
}
DEV bf16x8 read_swz(const unsigned short* buf, int row, int lc) {
  int pc = lc ^ (row & 7);
  return *(const bf16x8*)&buf[row * 64 + pc * 8];
}

// ---------------- flash attention, split-j, shuffle-gathered T -------------
// grid (x=bh 32, y = i-tile*2 + split). Each block: 8 j-tiles of 64.
// Partials: Opart[split][bh][1024][64] bf16 (unnormalized), lpart f32.
// T band: T[dl][u]=q_dl.rel[clamp(tb+u)]; consumer gathers from same quad
// group via shfl: src=quad*16+((15+dl-q15)&15), reg ub=((63+dl-q15)>>4)-cb.
__global__ __launch_bounds__(256)
void flash_attn(const unsigned short* __restrict__ q_ws,   // pre-scaled .125
                const unsigned short* __restrict__ k_ws,
                const unsigned short* __restrict__ vt_ws,  // [bh][64][1024]
                const unsigned short* __restrict__ rel,    // [1025][64]
                unsigned short* __restrict__ Opart,        // [2][32][1024][64]
                float* __restrict__ lpart) {               // [2][32*1024]
  __shared__ __align__(16) unsigned short Kbuf[64 * 64];
  __shared__ __align__(16) unsigned short Vbuf[64 * 64];
  __shared__ __align__(16) unsigned short P_lds[4][16][72];

  const int tid  = threadIdx.x;
  const int lane = tid & 63, w = tid >> 6;
  const int q15  = lane & 15, quad = lane >> 4;
  const int bh = blockIdx.x;
  const int it = blockIdx.y >> 1, sp = blockIdx.y & 1;
  const int ib = it * 64 + w * 16;
  const int jbase = sp * 512;

  const unsigned short* qp = q_ws  + (size_t)bh * 1024 * 64;
  const unsigned short* kp = k_ws  + (size_t)bh * 1024 * 64;
  const unsigned short* tp = vt_ws + (size_t)bh * 64 * 1024;

  bf16x8 aq[2];
  #pragma unroll
  for (int ks = 0; ks < 2; ++ks)
    aq[ks] = *(const bf16x8*)&qp[(size_t)(ib + q15) * 64 + ks * 32 + quad * 8];

  f32x4 o[4] = {};
  float l_i[4] = {0.f, 0.f, 0.f, 0.f};

  for (int jt = 0; jt < 8; ++jt) {
    const int j0 = jbase + jt * 64;
    stage16(kp + (size_t)j0 * 64, 64, &Kbuf[0], w * 16, lane);
    stage16(tp + j0, 1024, &Vbuf[0], w * 16, lane);
    __syncthreads();  // drains vmcnt -> staging visible to all waves

    // Q K^T
    f32x4 accS[4] = {};
    #pragma unroll
    for (int ks = 0; ks < 2; ++ks)
      #pragma unroll
      for (int cb = 0; cb < 4; ++cb) {
        bf16x8 bk = read_swz(&Kbuf[0], cb * 16 + q15, ks * 4 + quad);
        accS[cb] = __builtin_amdgcn_mfma_f32_16x16x32_bf16(aq[ks], bk, accS[cb], 0, 0, 0);
      }
    // positional band T[16][80] in MFMA C-layout registers
    int tb = ib - j0 + 512 - 63;
    f32x4 accT[5] = {};
    #pragma unroll
    for (int ks = 0; ks < 2; ++ks)
      #pragma unroll
      for (int ub = 0; ub < 5; ++ub) {
        int trow = tb + ub * 16 + q15;
        trow = trow < 0 ? 0 : (trow > 1024 ? 1024 : trow);
        bf16x8 br = *(const bf16x8*)&rel[(size_t)trow * 64 + ks * 32 + quad * 8];
        accT[ub] = __builtin_amdgcn_mfma_f32_16x16x32_bf16(aq[ks], br, accT[ub], 0, 0, 0);
      }

    // softmax numerators: gather T via shuffles (same quad group), exp, P
    #pragma unroll
    for (int r = 0; r < 4; ++r) {
      const int dl = quad * 4 + r;
      const int src = quad * 16 + ((15 + dl - q15) & 15);
      float tv[5];
      #pragma unroll
      for (int ub = 0; ub < 5; ++ub)
        tv[ub] = __shfl(accT[ub][r], src, 64);
      const bool hi = (q15 < dl);  // (63+dl-q15) >= 64
      #pragma unroll
      for (int cb = 0; cb < 4; ++cb) {
        float tval = hi ? tv[4 - cb] : tv[3 - cb];
        float s = accS[cb][r] + tval;
        float p = exp2f(s * 1.44269504f - 64.f);
        l_i[r] += p;
        P_lds[w][dl][cb * 16 + q15] = f2bf(p);
      }
    }

    // O += P @ V (P per-wave LDS roundtrip; V^T swizzled)
    #pragma unroll
    for (int ks = 0; ks < 2; ++ks) {
      bf16x8 ap = *(const bf16x8*)&P_lds[w][q15][ks * 32 + quad * 8];
      #pragma unroll
      for (int db = 0; db < 4; ++db) {
        bf16x8 bv = read_swz(&Vbuf[0], db * 16 + q15, ks * 4 + quad);
        o[db] = __builtin_amdgcn_mfma_f32_16x16x32_bf16(ap, bv, o[db], 0, 0, 0);
      }
    }
    __syncthreads();  // all waves done reading Kbuf/Vbuf before restage
  }

  // l: reduce across the 16 lanes of each quad group
  #pragma unroll
  for (int r = 0; r < 4; ++r)
    #pragma unroll
    for (int off = 1; off < 16; off <<= 1)
      l_i[r] += __shfl_xor(l_i[r], off, 64);

  unsigned short* op = Opart + ((size_t)sp * 32 + bh) * 1024 * 64;
  #pragma unroll
  for (int db = 0; db < 4; ++db)
    #pragma unroll
    for (int r = 0; r < 4; ++r) {
      int row = ib + quad * 4 + r;
      op[(size_t)row * 64 + db * 16 + q15] = f2bf(o[db][r]);
    }
  if (q15 == 0)
    #pragma unroll
    for (int r = 0; r < 4; ++r)
      lpart[(size_t)sp * 32768 + bh * 1024 + ib + quad * 4 + r] = l_i[r];
}

// ---- combine partials -> ao[b*1024+i][h*64+d] bf16 ------------------------
__global__ __launch_bounds__(256)
void combine_k(const unsigned short* __restrict__ Opart,
               const float* __restrict__ lpart,
               unsigned short* __restrict__ ao) {
  int e = (blockIdx.x * 256 + threadIdx.x) * 4;  // 2M elements, 4 per thread
  if (e >= 2097152) return;
  int bh = e >> 16, rem = e & 65535, row = rem >> 6, d = e & 63;
  size_t off = (size_t)bh * 65536 + rem;
  const unsigned short* p0 = Opart + off;
  const unsigned short* p1 = Opart + 2097152 + off;
  float li = 1.f / (lpart[bh * 1024 + row] + lpart[32768 + bh * 1024 + row] + 1e-30f);
  ushort2 a0 = *(const ushort2*)p0, a1 = *(const ushort2*)(p0 + 2);
  ushort2 b0 = *(const ushort2*)p1, b1 = *(const ushort2*)(p1 + 2);
  int b = bh >> 4, h = bh & 15;
  unsigned short* dst = ao + ((size_t)(b * 1024 + row)) * 1024 + h * 64 + d;
  dst[0] = f2bf((bf2f(a0.x) + bf2f(b0.x)) * li);
  dst[1] = f2bf((bf2f(a0.y) + bf2f(b0.y)) * li);
  dst[2] = f2bf((bf2f(a1.x) + bf2f(b1.x)) * li);
  dst[3] = f2bf((bf2f(a1.y) + bf2f(b1.y)) * li);
}

// ---------------- GEMM out = ao @ WoT^T + bo (f32 out), 128x64 tiles -------
__global__ __launch_bounds__(256)
void gemm_out(const unsigned short* __restrict__ A,
              const unsigned short* __restrict__ Bt,
              const unsigned short* __restrict__ bias,
              float* __restrict__ fo) {
  __shared__ __align__(16) unsigned short As[128][32];
  __shared__ __align__(16) unsigned short Bs[64][32];
  const int tid  = threadIdx.x;
  const int lane = tid & 63, w = tid >> 6;
  const int q15  = lane & 15, quad = lane >> 4;
  const int m0 = blockIdx.y * 128, n0 = blockIdx.x * 64;
  const int K = 1024, N = 1024;
  const int lrow = lane >> 2, lkc = (lane & 3) * 8;

  f32x4 acc[2][4] = {};
  for (int k0 = 0; k0 < K; k0 += 32) {
    __syncthreads();
    #pragma unroll
    for (int t = 0; t < 2; ++t) {
      int r0 = w * 32 + t * 16;
      load_lds16(&A[(size_t)(m0 + r0 + lrow) * K + k0 + lkc], &As[r0][0]);
    }
    load_lds16(&Bt[(size_t)(n0 + w * 16 + lrow) * K + k0 + lkc], &Bs[w * 16][0]);
    __syncthreads();
    bf16x8 af[2], bfr[4];
    #pragma unroll
    for (int i = 0; i < 2; ++i)
      af[i] = *(const bf16x8*)&As[w * 32 + i * 16 + q15][quad * 8];
    #pragma unroll
    for (int j = 0; j < 4; ++j)
      bfr[j] = *(const bf16x8*)&Bs[j * 16 + q15][quad * 8];
    #pragma unroll
    for (int i = 0; i < 2; ++i)
      #pragma unroll
      for (int j = 0; j < 4; ++j)
        acc[i][j] = __builtin_amdgcn_mfma_f32_16x16x32_bf16(af[i], bfr[j], acc[i][j], 0, 0, 0);
  }
  #pragma unroll
  for (int i = 0; i < 2; ++i)
    #pragma unroll
    for (int j = 0; j < 4; ++j)
      #pragma unroll
      for (int r = 0; r < 4; ++r) {
        int row = m0 + w * 32 + i * 16 + quad * 4 + r;
        int col = n0 + j * 16 + q15;
        fo[(size_t)row * N + col] = acc[i][j][r] + bf2f(bias[col]);
      }
}

// ---------------------------------------------------------------------------
extern "C" void kernel_launch(void* const* d_in, const int* in_sizes, int n_in,
                              void* d_out, int out_size, void* d_ws, size_t ws_size,
                              hipStream_t stream) {
  (void)in_sizes; (void)n_in; (void)out_size; (void)ws_size;
  const float* x   = (const float*)d_in[0];
  const float* Wq  = (const float*)d_in[1];
  const float* Wkv = (const float*)d_in[2];
  const float* Wo  = (const float*)d_in[3];
  const float* bo  = (const float*)d_in[4];
  const float* rel = (const float*)d_in[5];
  float* out = (float*)d_out;

  unsigned short* ws = (unsigned short*)d_ws;
  unsigned short* WoT   = ws;                      // 1,048,576
  unsigned short* relb  = WoT   + 1048576;         // 65,664 reserved
  unsigned short* bob   = relb  + 65664;           // 1,088 reserved
  unsigned short* q_ws  = bob   + 1088;            // 2,097,152
  unsigned short* k_ws  = q_ws  + 2097152;         // 2,097,152
  unsigned short* vT    = k_ws  + 2097152;         // 2,097,152
  unsigned short* WqkvT = vT    + 2097152;         // 3,145,728 (dead after gemm1)
  unsigned short* xb    = WqkvT + 3145728;         // 2,097,152 (dead after gemm1)
  unsigned short* v_row = xb    + 2097152;         // 2,097,152 (dead after trans_v)
  float*          lpart = (float*)(v_row + 2097152); // 65,536 f32 = 131,072 sh
  // aliases:
  unsigned short* Opart = WqkvT;  // 2 x 2,097,152 bf16 over WqkvT+xb (5.2M av.)
  unsigned short* ao    = v_row;  // combine output over v_row

  prep_k<<<6210, 256, 0, stream>>>(x, rel, bo, Wq, Wkv, Wo,
                                   xb, relb, bob, WqkvT, WoT);
  gemm_qkv<<<dim3(24, 16), 256, 0, stream>>>(xb, WqkvT, q_ws, k_ws, v_row);
  transpose_v_k<<<dim3(16, 32), 256, 0, stream>>>(v_row, vT);
  flash_attn<<<dim3(32, 32), 256, 0, stream>>>(q_ws, k_ws, vT, relb, Opart, lpart);
  combine_k<<<2048, 256, 0, stream>>>(Opart, lpart, ao);
  gemm_out<<<dim3(16, 16), 256, 0, stream>>>(ao, WoT, bob, out);
}